// Round 21
// baseline (2957.699 us; speedup 1.0000x reference)
//
#include <hip/hip_runtime.h>

typedef __bf16 bf16;
typedef __bf16 bf16x4 __attribute__((ext_vector_type(4)));
typedef __bf16 bf16x8 __attribute__((ext_vector_type(8)));
typedef float  f32x4  __attribute__((ext_vector_type(4)));
typedef unsigned int u32;

#define GLD_LDS16(gsrc, ldst) \
  __builtin_amdgcn_global_load_lds((const __attribute__((address_space(1))) u32*)(gsrc), \
                                   (__attribute__((address_space(3))) u32*)(ldst), 16, 0, 0)

static __device__ __forceinline__ float sigmoidf_(float x) { return 1.0f / (1.0f + expf(-x)); }

__global__ void fill_guard(float* __restrict__ utt, float v) {
  int i = blockIdx.x * 256 + threadIdx.x;
  if (i < 131072) utt[i] = v;
}

// ---------------- H = bf16(x + pos_emb) ----------------
__global__ void add_pos_bf(const float* __restrict__ x, const float* __restrict__ pos,
                           bf16* __restrict__ H) {
  size_t i = ((size_t)blockIdx.x * 256 + threadIdx.x) * 4;
  if (i >= 32768000ull) return;
  int d = (int)(i & 1023);
  int s = (int)((i >> 10) % 500);
  float4 xv = *(const float4*)(x + i);
  float4 pv = *(const float4*)(pos + (size_t)s * 1024 + d);
  bf16x4 o;
  o[0] = (bf16)(xv.x + pv.x); o[1] = (bf16)(xv.y + pv.y);
  o[2] = (bf16)(xv.z + pv.z); o[3] = (bf16)(xv.w + pv.w);
  *(bf16x4*)(H + i) = o;
}

// ---------------- weight transpose+convert: fp32 [R][C] -> bf16 [C][R] ----------------
__global__ void wtrans(const float* __restrict__ src, bf16* __restrict__ dst, int R, int C) {
  __shared__ float tile[32][33];
  int c0 = blockIdx.x * 32, r0 = blockIdx.y * 32;
  int tr = threadIdx.x >> 5, tc = threadIdx.x & 31;
#pragma unroll
  for (int i = 0; i < 4; ++i)
    tile[tr + i * 8][tc] = src[(size_t)(r0 + tr + i * 8) * C + c0 + tc];
  __syncthreads();
#pragma unroll
  for (int i = 0; i < 4; ++i) {
    int rr = tr + i * 8;
    dst[(size_t)(c0 + rr) * R + r0 + tc] = (bf16)tile[tc][rr];
  }
}

// ========== 256x256 BK=64 8-wave GEMM, 2-phase issue-early dbuf, counted vmcnt ==========
// Per iter: STAGE(t+1 -> buf^1) issued FIRST; vmcnt(8) waits tile t only; barrier;
// per-ks {ds_read frags, setprio MFMA}; barrier. Swizzle chunk^=(row&7) (16B units).
// EPI 0 plain / 1 sigmoid / 2 gate mix (dual-write f32+bf16) / 4 fused QKV proj.
template <int EPI, typename TC>
__global__ __launch_bounds__(512, 2) void mgemm256d(
    const bf16* __restrict__ A, const bf16* __restrict__ A2, int ksplit,
    const bf16* __restrict__ Bt, const float* __restrict__ bias,
    const float* __restrict__ biasK, const float* __restrict__ biasV,
    TC* __restrict__ C, bf16* __restrict__ Cbf, bf16* __restrict__ Cv,
    int M, int N, int K, int lda, int ldb, int ldc, int c_off, float scale,
    const bf16* __restrict__ Gh, const bf16* __restrict__ Gm) {
  extern __shared__ char sm[];  // buf c @ c*65536: A 32KB @0, B 32KB @32768
  const int t = threadIdx.x;

  // T1: bijective XCD-aware block remap (m204)
  const int gx = gridDim.x;
  const int nwg = gx * gridDim.y;
  const int orig = blockIdx.y * gx + blockIdx.x;
  const int qq = nwg >> 3, r8 = nwg & 7;
  const int xcd = orig & 7, lo = orig >> 3;
  const int wg = (xcd < r8 ? xcd * (qq + 1) : r8 * (qq + 1) + (xcd - r8) * qq) + lo;
  const int m0 = (wg / gx) * 256, n0 = (wg % gx) * 256;

  const int lane = t & 63;
  const int w = t >> 6, wr = w >> 2, wc = w & 3;  // 2x4 waves, each 128x64 out
  const int lr = lane & 15, lhi = lane >> 4;
  const int srow = t >> 3, sch = t & 7;  // staging: 64-row groups, 8 chunks/row

  f32x4 acc[8][4];
#pragma unroll
  for (int i = 0; i < 8; ++i)
#pragma unroll
    for (int j = 0; j < 4; ++j)
#pragma unroll
      for (int c = 0; c < 4; ++c) acc[i][j][c] = 0.0f;

  // stage full K-tile tt (A 256x64 + B 256x64) into buffer cb: 8 GLD / thread
#define STAGE_T(tt, cb) do {                                                         \
    const int k0s_ = (tt) * 64;                                                      \
    char* ba_ = sm + (cb) * 65536;                                                   \
    _Pragma("unroll")                                                                \
    for (int i_ = 0; i_ < 4; ++i_) {                                                 \
      int rl_ = i_ * 64 + srow;                                                      \
      int ra_ = m0 + rl_; ra_ = ra_ < M ? ra_ : M - 1;                               \
      int ca_ = (sch ^ (ra_ & 7)) * 8;                                               \
      const bf16* s_ = (k0s_ < ksplit)                                               \
          ? A  + (size_t)ra_ * lda + k0s_ + ca_                                      \
          : A2 + (size_t)ra_ * lda + (k0s_ - ksplit) + ca_;                          \
      GLD_LDS16(s_, ba_ + rl_ * 128 + sch * 16);                                     \
      int rb_ = n0 + rl_; rb_ = rb_ < N ? rb_ : N - 1;                               \
      int cb_ = (sch ^ (rb_ & 7)) * 8;                                               \
      GLD_LDS16(Bt + (size_t)rb_ * ldb + k0s_ + cb_, ba_ + 32768 + rl_ * 128 + sch * 16); \
    }                                                                                \
  } while (0)

  const int NT = K >> 6;
  STAGE_T(0, 0);

  for (int t0 = 0; t0 < NT; ++t0) {
    const int cur = t0 & 1;
    char* smA = sm + cur * 65536;
    char* smB = smA + 32768;
    const bool pf = (t0 + 1 < NT);

    if (pf) {
      STAGE_T(t0 + 1, cur ^ 1);                       // issue next tile FIRST
      asm volatile("s_waitcnt vmcnt(8)" ::: "memory"); // wait current tile only
    } else {
      asm volatile("s_waitcnt vmcnt(0)" ::: "memory");
    }
    __builtin_amdgcn_s_barrier();

#pragma unroll
    for (int ks = 0; ks < 2; ++ks) {
      bf16x8 av[8], bv[4];
#pragma unroll
      for (int fr = 0; fr < 8; ++fr) {
        int ra = wr * 128 + fr * 16 + lr;
        int ga = ks * 4 + lhi;
        av[fr] = *(const bf16x8*)(smA + ra * 128 + ((ga ^ (ra & 7)) << 4));
      }
#pragma unroll
      for (int fc = 0; fc < 4; ++fc) {
        int rb = wc * 64 + fc * 16 + lr;
        int ga = ks * 4 + lhi;
        bv[fc] = *(const bf16x8*)(smB + rb * 128 + ((ga ^ (rb & 7)) << 4));
      }
      __builtin_amdgcn_s_setprio(1);
#pragma unroll
      for (int fr = 0; fr < 8; ++fr)
#pragma unroll
        for (int fc = 0; fc < 4; ++fc)
          acc[fr][fc] = __builtin_amdgcn_mfma_f32_16x16x32_bf16(av[fr], bv[fc],
                                                                acc[fr][fc], 0, 0, 0);
      __builtin_amdgcn_s_setprio(0);
    }
    __builtin_amdgcn_s_barrier();
  }
#undef STAGE_T

  // epilogue: m = m0+wr*128+fr*16+lhi*4+j4, n = n0+wc*64+fc*16+lr
#pragma unroll
  for (int fr = 0; fr < 8; ++fr) {
#pragma unroll
    for (int j4 = 0; j4 < 4; ++j4) {
      int m = m0 + wr * 128 + fr * 16 + lhi * 4 + j4;
      if (m >= M) continue;
#pragma unroll
      for (int fc = 0; fc < 4; ++fc) {
        int n = n0 + wc * 64 + fc * 16 + lr;
        if (n >= N) continue;
        float v = acc[fr][fc][j4] * scale;
        if (EPI == 4) {
          const float* bp = (n < 1024) ? bias : (n < 2048) ? biasK : biasV;
          v += bp[n & 1023];
          unsigned b = (unsigned)m / 500u;
          unsigned s = (unsigned)m - b * 500u;
          if (n < 1024)       C  [(size_t)m * 1024 + n] = (TC)v;
          else if (n < 2048)  Cbf[(size_t)m * 1024 + (n - 1024)] = (bf16)v;
          else                Cv [(size_t)b * 524288 + (size_t)(n - 2048) * 512 + s] = (bf16)v;
          continue;
        }
        if (bias) v += bias[n];
        if (EPI == 1) v = sigmoidf_(v);
        if (EPI == 2) {
          float g = sigmoidf_(v);
          float h  = (float)Gh[(size_t)m * 1024 + n];
          float hm = (float)Gm[(size_t)m * 1024 + n];
          v = g * h + (1.0f - g) * hm;
        }
        C[(size_t)m * ldc + c_off + n] = (TC)v;
        if (EPI == 2 && Cbf) Cbf[(size_t)m * 2048 + c_off + n] = (bf16)v;
      }
    }
  }
}

// ---------------- 128x128 BK=64 MFMA GEMM (R20-proven; QK^T / PV batched) ----------------
template <int EPI, typename TC>
__global__ __launch_bounds__(256, 2) void mgemm(
    const bf16* __restrict__ A, const bf16* __restrict__ Bt, TC* __restrict__ C,
    int M, int N, int K, int lda, int ldb, int ldc, float scale,
    long long sA, long long sB, long long sC) {
  __shared__ __align__(16) char sm[32768];
  const int t = threadIdx.x;
  const long long bz = blockIdx.z;
  A += bz * sA; Bt += bz * sB; C += bz * sC;

  const int gx = gridDim.x;
  const int nwg = gx * gridDim.y;
  const int orig = blockIdx.y * gx + blockIdx.x;
  const int qq = nwg >> 3, r8 = nwg & 7;
  const int xcd = orig & 7, lo = orig >> 3;
  const int wg = (xcd < r8 ? xcd * (qq + 1) : r8 * (qq + 1) + (xcd - r8) * qq) + lo;
  const int m0 = (wg / gx) * 128, n0 = (wg % gx) * 128;

  f32x4 acc[4][4];
#pragma unroll
  for (int i = 0; i < 4; ++i)
#pragma unroll
    for (int j = 0; j < 4; ++j)
#pragma unroll
      for (int c = 0; c < 4; ++c) acc[i][j][c] = 0.0f;

  const int lane = t & 63;
  const int wv = t >> 6, wm = (wv >> 1) * 64, wn = (wv & 1) * 64;
  const int lr = lane & 15, lhi = lane >> 4;
  const int srow8 = t >> 3, sch = t & 7;

  for (int k0 = 0; k0 < K; k0 += 64) {
    const bf16* Ak = A + k0;
    const bf16* Bk = Bt + k0;
#pragma unroll
    for (int i = 0; i < 4; ++i) {
      int rl = i * 32 + srow8;
      int ra = m0 + rl; ra = ra < M ? ra : M - 1;
      int ca = (sch ^ (ra & 7)) * 8;
      GLD_LDS16(Ak + (size_t)ra * lda + ca, sm + rl * 128 + sch * 16);
      int rb = n0 + rl; rb = rb < N ? rb : N - 1;
      int cb = (sch ^ (rb & 7)) * 8;
      GLD_LDS16(Bk + (size_t)rb * ldb + cb, sm + 16384 + rl * 128 + sch * 16);
    }
    asm volatile("s_waitcnt vmcnt(0)" ::: "memory");
    __syncthreads();

    bf16x8 av[4][2], bv[4][2];
#pragma unroll
    for (int i = 0; i < 4; ++i)
#pragma unroll
      for (int ks = 0; ks < 2; ++ks) {
        int ra = wm + i * 16 + lr;
        int ga = ks * 4 + lhi;
        av[i][ks] = *(const bf16x8*)(sm + ra * 128 + ((ga ^ (ra & 7)) << 4));
        int rb = wn + i * 16 + lr;
        bv[i][ks] = *(const bf16x8*)(sm + 16384 + rb * 128 + ((ga ^ (rb & 7)) << 4));
      }
#pragma unroll
    for (int ks = 0; ks < 2; ++ks)
#pragma unroll
      for (int i = 0; i < 4; ++i)
#pragma unroll
        for (int j = 0; j < 4; ++j)
          acc[i][j] = __builtin_amdgcn_mfma_f32_16x16x32_bf16(av[i][ks], bv[j][ks],
                                                              acc[i][j], 0, 0, 0);
    __syncthreads();
  }

#pragma unroll
  for (int i = 0; i < 4; ++i) {
#pragma unroll
    for (int j4 = 0; j4 < 4; ++j4) {
      int m = m0 + wm + i * 16 + lhi * 4 + j4;
      if (m >= M) continue;
#pragma unroll
      for (int j = 0; j < 4; ++j) {
        int n = n0 + wn + j * 16 + lr;
        if (n >= N) continue;
        C[(size_t)m * ldc + n] = (TC)(acc[i][j][j4] * scale);
      }
    }
  }
}

// ---------------- masked softmax, wave-parallel ----------------
__global__ void attn_softmax_w(const float* __restrict__ S, bf16* __restrict__ P, int fw) {
  int row = blockIdx.x * 4 + (threadIdx.x >> 6);
  int lane = threadIdx.x & 63;
  int q = row % 500;
  const float* Srow = S + (size_t)row * 512;
  bf16* Prow = P + (size_t)row * 512;
  int klo = fw ? 0 : q;
  int khi = fw ? q : 499;

  float xv[8];
  float m = -1e30f;
#pragma unroll
  for (int i = 0; i < 8; ++i) {
    int k = lane + i * 64;
    bool valid = (k >= klo) & (k <= khi);
    float v = valid ? Srow[k] : -1e30f;
    xv[i] = v;
    m = fmaxf(m, v);
  }
#pragma unroll
  for (int off = 32; off > 0; off >>= 1) m = fmaxf(m, __shfl_xor(m, off, 64));
  float e[8];
  float sum = 0.0f;
#pragma unroll
  for (int i = 0; i < 8; ++i) {
    e[i] = (xv[i] > -1e29f) ? expf(xv[i] - m) : 0.0f;
    sum += e[i];
  }
#pragma unroll
  for (int off = 32; off > 0; off >>= 1) sum += __shfl_xor(sum, off, 64);
  float inv = 1.0f / sum;
#pragma unroll
  for (int i = 0; i < 8; ++i) Prow[lane + i * 64] = (bf16)(e[i] * inv);
}

// ---------------- final: online softmax over seq + weighted sum ----------------
__global__ void final_reduce_chunk(const float* __restrict__ s2, const float* __restrict__ Ci,
                                   float* __restrict__ utt) {
  int c = blockIdx.x * 256 + threadIdx.x;
  int b = blockIdx.y;
  if (c >= 2048) return;
  float m = -1e30f, sum = 0.0f, acc = 0.0f;
  for (int s = 0; s < 500; ++s) {
    size_t idx = ((size_t)(b * 500 + s)) * 2048 + c;
    float xx = s2[idx];
    float ci = Ci[idx];
    float mn = fmaxf(m, xx);
    float corr = expf(m - mn);
    float e = expf(xx - mn);
    sum = sum * corr + e;
    acc = acc * corr + e * ci;
    m = mn;
  }
  utt[(size_t)b * 2048 + c] = acc / sum;
}

// ---------------- launcher ----------------
extern "C" void kernel_launch(void* const* d_in, const int* in_sizes, int n_in,
                              void* d_out, int out_size, void* d_ws, size_t ws_size,
                              hipStream_t stream) {
  (void)in_sizes; (void)n_in; (void)out_size;
  float* utt = (float*)d_out;
  float* Ci  = (float*)d_out + 131072;

  const float* x     = (const float*)d_in[0];
  const float* pos   = (const float*)d_in[1];
  const float* Wq_fw = (const float*)d_in[2];  const float* bq_fw = (const float*)d_in[3];
  const float* Wk_fw = (const float*)d_in[4];  const float* bk_fw = (const float*)d_in[5];
  const float* Wv_fw = (const float*)d_in[6];  const float* bv_fw = (const float*)d_in[7];
  const float* Wq_bw = (const float*)d_in[8];  const float* bq_bw = (const float*)d_in[9];
  const float* Wk_bw = (const float*)d_in[10]; const float* bk_bw = (const float*)d_in[11];
  const float* Wv_bw = (const float*)d_in[12]; const float* bv_bw = (const float*)d_in[13];
  const float* Wg_fw = (const float*)d_in[14]; const float* bg_fw = (const float*)d_in[15];
  const float* Wg_bw = (const float*)d_in[16]; const float* bg_bw = (const float*)d_in[17];
  const float* W2    = (const float*)d_in[18]; const float* b2    = (const float*)d_in[19];
  const float* W1    = (const float*)d_in[20]; const float* b1    = (const float*)d_in[21];

  const size_t WS_BYTES = 465305600ull;
  if (ws_size < WS_BYTES) { fill_guard<<<512, 256, 0, stream>>>(utt, 500.0f); return; }

  char* wsb = (char*)d_ws;
  bf16*  Hbf  = (bf16*)(wsb);
  bf16*  Qb   = (bf16*)(wsb + 65536000);
  bf16*  Kb   = (bf16*)(wsb + 131072000);
  bf16*  Vt   = (bf16*)(wsb + 196608000);
  float* Sb   = (float*)(wsb + 263716864);
  bf16*  Hmb  = (bf16*)(wsb + 263716864);   // alias S after softmax
  bf16*  Pb   = (bf16*)(wsb + 329252864);
  char*  wts  = wsb + 362020864;
  bf16* WqF = (bf16*)(wts);             // WqF/WkF/WvF contiguous -> fused proj B (N=3072)
  bf16* WqB = (bf16*)(wts + 6291456);   // WqB/WkB/WvB contiguous
  bf16* WgF = (bf16*)(wts + 12582912);  bf16* WgB = (bf16*)(wts + 16777216);
  bf16* W2t = (bf16*)(wts + 20971520);  bf16* W1t = (bf16*)(wts + 29360128);
  bf16*  Cibf  = (bf16*)(wsb + 399769600);
  bf16*  activ = (bf16*)(wsb + 131072000);  // alias K+Vt head (post-attention)
  float* s2b   = (float*)(wsb);             // alias Hbf+Q (post-gates)

  hipFuncSetAttribute(reinterpret_cast<const void*>(&mgemm256d<4, bf16>),
                      hipFuncAttributeMaxDynamicSharedMemorySize, 131072);
  hipFuncSetAttribute(reinterpret_cast<const void*>(&mgemm256d<2, float>),
                      hipFuncAttributeMaxDynamicSharedMemorySize, 131072);
  hipFuncSetAttribute(reinterpret_cast<const void*>(&mgemm256d<1, bf16>),
                      hipFuncAttributeMaxDynamicSharedMemorySize, 131072);
  hipFuncSetAttribute(reinterpret_cast<const void*>(&mgemm256d<0, float>),
                      hipFuncAttributeMaxDynamicSharedMemorySize, 131072);

  add_pos_bf<<<32000, 256, 0, stream>>>(x, pos, Hbf);

  struct WT { const float* s; bf16* d; int R, C; } wt[10] = {
      {Wq_fw, WqF, 1024, 1024}, {Wk_fw, (bf16*)(wts + 2097152), 1024, 1024},
      {Wv_fw, (bf16*)(wts + 4194304), 1024, 1024}, {Wq_bw, WqB, 1024, 1024},
      {Wk_bw, (bf16*)(wts + 8388608), 1024, 1024}, {Wv_bw, (bf16*)(wts + 10485760), 1024, 1024},
      {Wg_fw, WgF, 2048, 1024}, {Wg_bw, WgB, 2048, 1024},
      {W2,    W2t, 2048, 2048}, {W1,    W1t, 2048, 2048}};
  for (int i = 0; i < 10; ++i)
    wtrans<<<dim3(wt[i].C / 32, wt[i].R / 32), 256, 0, stream>>>(wt[i].s, wt[i].d, wt[i].R, wt[i].C);

  const int BIG = 1 << 30;
  for (int dir = 0; dir < 2; ++dir) {
    const bf16* WqkvT = dir ? WqB : WqF;   // contiguous [3072][1024]
    const bf16* WgT = dir ? WgB : WgF;
    const float* bq = dir ? bq_bw : bq_fw;
    const float* bk = dir ? bk_bw : bk_fw;
    const float* bv = dir ? bv_bw : bv_fw;
    const float* bg = dir ? bg_bw : bg_fw;

    // fused Q/K/Vt projection: [32000,1024] x [3072,1024]^T  (256^2 dbuf)
    mgemm256d<4, bf16><<<dim3(12, 125), 512, 131072, stream>>>(
        Hbf, Hbf, BIG, WqkvT, bq, bk, bv, Qb, Kb, Vt,
        32000, 3072, 1024, 1024, 1024, 1024, 0, 1.0f, nullptr, nullptr);
    // S = Q K^T / 32   f32 [64][500][512]
    mgemm<0, float><<<dim3(4, 4, 64), 256, 0, stream>>>(
        Qb, Kb, Sb, 500, 500, 1024, 1024, 1024, 512, 0.03125f,
        512000, 512000, 256000);
    attn_softmax_w<<<8000, 256, 0, stream>>>(Sb, Pb, dir == 0 ? 1 : 0);
    // Hm = P @ V   (K=512)
    mgemm<0, bf16><<<dim3(8, 4, 64), 256, 0, stream>>>(
        Pb, Vt, Hmb, 500, 1024, 512, 512, 512, 1024, 1.0f,
        256000, 524288, 512000);
    // gate -> f32 Ci + bf16 Cibf (split A at 1024)  (256^2 dbuf)
    mgemm256d<2, float><<<dim3(8, 125), 512, 131072, stream>>>(
        Hbf, Hmb, 1024, WgT, bg, nullptr, nullptr, Ci, Cibf, nullptr,
        32000, 1024, 2048, 1024, 2048, 2048, dir == 0 ? 0 : 1024, 1.0f, Hbf, Hmb);
  }

  // activ = sigmoid(Cibf @ W2 + b2)  (256^2 dbuf)
  mgemm256d<1, bf16><<<dim3(8, 125), 512, 131072, stream>>>(
      Cibf, Cibf, BIG, W2t, b2, nullptr, nullptr, activ, nullptr, nullptr,
      32000, 2048, 2048, 2048, 2048, 2048, 0, 1.0f, nullptr, nullptr);

  // scores2 + online final reduce in 2 chunks of 32 batches  (256^2 dbuf)
  for (int c0 = 0; c0 < 2; ++c0) {
    mgemm256d<0, float><<<dim3(8, 63), 512, 131072, stream>>>(
        activ + (size_t)c0 * 16000 * 2048, activ, BIG, W1t, b1, nullptr, nullptr,
        s2b, nullptr, nullptr, 16000, 2048, 2048, 2048, 2048, 2048, 0, 1.0f,
        nullptr, nullptr);
    final_reduce_chunk<<<dim3(8, 32), 256, 0, stream>>>(
        s2b, Ci + (size_t)c0 * 32 * 500 * 2048, utt + (size_t)c0 * 32 * 2048);
  }
}